// Round 1
// baseline (818.537 us; speedup 1.0000x reference)
//
#include <hip/hip_runtime.h>
#include <stdint.h>

// Fused single-pass: out[b, seg, np, chunk, p, 4, 4] = mean over chunk frames
// of [x;1][x;1]^T.  stypes 0/1/2: chunk len 136/68/45, out segs {0},{1,2},
// {3,4,5}; tail chunks run to T=2048 (reference slices from start of T and
// tails to the END of T, so equal nb_fr segments are duplicates).
//
// Phase A (all blocks, grid (piece, b) = 36 x 256): thread t<250 =
// (fslot=t/25, j=t%25) accumulates 9 moments in registers straight from
// global; per step k the block's 250 lanes read 750 contiguous floats.
// One LDS reduction -> 225-float ws slice per (b,piece).
//
// Phase B (last-arriving block per b, via device-scope atomic counter):
// gathers the 36 piece slices for its b, reduces piece->chunk per the
// host-precomputed ranges, finalizes 4x4s, coalesced float4 stores for all
// 5 np.  This overlaps the output writes with other b's streaming reads and
// removes the device-wide drain the old p1->p2 launch boundary imposed.

#define NSEG_MAX 40
#define IDXPK 0x9210287517640543ull   // 4x4 row r -> moment idx nibbles (9=dummy)

struct Tab {
    int n;                        // 36
    uint32_t p[NSEG_MAX];         // f0 | (len<<16)
    uint32_t cr[45];              // per (stype*15+chunk): pstart | (pend<<16)
};

// ---------------- Fused kernel ----------------
__global__ __launch_bounds__(256) void fused_kernel(const float* __restrict__ x,
                                                    float* __restrict__ ws,
                                                    unsigned* __restrict__ cnt,
                                                    float* __restrict__ out, Tab tab) {
    // Overlaid LDS: phase A uses [0,2250); phase B uses sws[0,1800) +
    // red[1800,3825) + invn[3825,3870).  15.5 KB -> still 8 blocks/CU.
    __shared__ float smem[3870];
    __shared__ int lastFlag;
    int pc = blockIdx.x, b = blockIdx.y;
    int n = tab.n;
    uint32_t pk = tab.p[pc];
    int f0 = pk & 0xffff, L = (int)(pk >> 16);   // 8 <= L <= 144
    int tid = threadIdx.x;

    // ---- Phase A: per-(b,piece) moment sums ----
    if (tid < 250) {
        int fslot = tid / 25;                    // 0..9
        const float* q = x + (size_t)b * 153600 + (size_t)f0 * 75 + tid * 3;
        int nk = (L - fslot + 9) / 10;           // frames fslot, fslot+10, ...
        float s0=0.f,s1=0.f,s2=0.f,s3=0.f,s4=0.f,s5=0.f,s6=0.f,s7=0.f,s8=0.f;
        #pragma unroll 5
        for (int k = 0; k < nk; ++k, q += 750) {
            float a = q[0], bb = q[1], c = q[2];
            s0 += a;       s1 += bb;      s2 += c;
            s3 += a * a;   s4 += a * bb;  s5 += a * c;
            s6 += bb * bb; s7 += bb * c;  s8 += c * c;
        }
        float* l = &smem[tid * 9];               // stride 9: conflict-benign
        l[0]=s0; l[1]=s1; l[2]=s2; l[3]=s3; l[4]=s4; l[5]=s5; l[6]=s6; l[7]=s7; l[8]=s8;
    }
    __syncthreads();
    if (tid < 225) {              // cell = j*9+si ; partial at smem[fs*225+cell]
        float v = 0.f;
        #pragma unroll
        for (int fs = 0; fs < 10; ++fs) v += smem[fs * 225 + tid];
        ws[((size_t)b * n + pc) * 225 + tid] = v;
    }
    __syncthreads();              // vmcnt(0): all ws stores of this block complete

    // ---- arrival: last block per b proceeds to phase B ----
    if (tid == 0) {
        __threadfence();                          // release ws slice (device scope)
        unsigned old = atomicAdd(&cnt[b], 1u);    // device-scope by default
        lastFlag = (old == (unsigned)(n - 1));
    }
    __syncthreads();
    if (!lastFlag) return;
    __threadfence();                              // acquire: invalidate stale cache

    // ---- Phase B: finalize all 5 np for this b ----
    float* sws  = smem;           // [piece][j_local*9+si], n*45
    float* red  = smem + 1800;    // [stype*15+chunk][j_local*9+si]
    float* invn = smem + 3825;
    if (tid < 45) {
        int st = tid / 15, ch = tid - st * 15;
        const int nst[3] = {136, 68, 45};
        int ns = nst[st];
        int nfr = (ch == 14) ? (2048 - 14 * ns) : ns;
        invn[tid] = 1.0f / (float)nfr;
    }
    const float* wbase = ws + (size_t)b * n * 225;
    float4* ob4b = (float4*)(out + (size_t)b * 36000);
    int tot = n * 45;
    for (int np = 0; np < 5; ++np) {
        for (int i = tid; i < tot; i += 256) {
            int piece = i / 45, idx = i - piece * 45;
            sws[i] = wbase[(size_t)piece * 225 + np * 45 + idx];  // 180 B runs
        }
        __syncthreads();          // (first iter: also covers invn)
        for (int i = tid; i < 2025; i += 256) {
            int sc = i / 45, idx = i - sc * 45;
            uint32_t r = tab.cr[sc];
            int p0 = (int)(r & 0xffff), p1 = (int)(r >> 16);
            float v = 0.f;
            for (int p = p0; p < p1; ++p) v += sws[p * 45 + idx];
            red[i] = v;
        }
        __syncthreads();
        // 1800 float4 stores: q -> (seg, chunk, p, row)
        float4* ob4 = ob4b + (size_t)np * 300;    // np*1200 floats
        for (int q = tid; q < 1800; q += 256) {
            int seg = q / 300;
            int q2  = q - seg * 300;              // ch*20 + p*4 + r
            int ch  = q2 / 20;
            int rem = q2 - ch * 20;
            int p   = rem >> 2;
            int r   = rem & 3;
            int st  = (seg == 0) ? 0 : (seg < 3) ? 1 : 2;
            int sc  = st * 15 + ch;
            float inv = invn[sc];
            const float* rb = &red[sc * 45 + p * 9];
            uint64_t pkk = IDXPK >> (16 * r);
            float4 v;
            v.x = rb[(int)(pkk & 15)] * inv;
            v.y = rb[(int)((pkk >> 4) & 15)] * inv;
            v.z = rb[(int)((pkk >> 8) & 15)] * inv;
            v.w = (r == 3) ? 1.0f : rb[(int)((pkk >> 12) & 15)] * inv;
            ob4[(size_t)seg * 1500 + q2] = v;
        }
        __syncthreads();          // red is rewritten next np while stores read it
    }
}

// ---------------- Fallback (round-1 fused, known-correct, no ws) ----------------
__global__ __launch_bounds__(256) void gauss_fallback(const float* __restrict__ x,
                                                      float* __restrict__ out) {
    __shared__ float lds[2250];
    __shared__ float red[225];
    __shared__ float outm[400];
    int bid = blockIdx.x;
    int chunk = bid % 15;
    int tmp = bid / 15;
    int stype = tmp % 3;
    int b = tmp / 3;
    const int nbs[3] = {136, 68, 45};
    int ns = nbs[stype];
    int f0 = chunk * ns;
    int f1 = (chunk == 14) ? 2048 : (f0 + ns);
    float inv_n = 1.0f / (float)(f1 - f0);
    int tid = threadIdx.x;
    if (tid < 250) {
        int j = tid % 25, tsub = tid / 25;
        const float* base = x + (size_t)b * 153600 + j * 3;
        float s0=0.f,s1=0.f,s2=0.f,s3=0.f,s4=0.f,s5=0.f,s6=0.f,s7=0.f,s8=0.f;
        for (int t = f0 + tsub; t < f1; t += 10) {
            const float* p = base + (size_t)t * 75;
            float x0 = p[0], x1 = p[1], x2 = p[2];
            s0+=x0; s1+=x1; s2+=x2;
            s3+=x0*x0; s4+=x0*x1; s5+=x0*x2;
            s6+=x1*x1; s7+=x1*x2; s8+=x2*x2;
        }
        float* l = &lds[tid * 9];
        l[0]=s0; l[1]=s1; l[2]=s2; l[3]=s3; l[4]=s4; l[5]=s5; l[6]=s6; l[7]=s7; l[8]=s8;
    }
    __syncthreads();
    if (tid < 225) {
        float v = 0.f;
        #pragma unroll
        for (int ts = 0; ts < 10; ++ts) v += lds[ts * 225 + tid];
        red[tid] = v;
    }
    __syncthreads();
    if (tid < 25) {
        const float* r = &red[tid * 9];
        float mu0=r[0]*inv_n, mu1=r[1]*inv_n, mu2=r[2]*inv_n;
        float m00=r[3]*inv_n, m01=r[4]*inv_n, m02=r[5]*inv_n;
        float m11=r[6]*inv_n, m12=r[7]*inv_n, m22=r[8]*inv_n;
        float* o = &outm[tid * 16];
        o[0]=m00; o[1]=m01; o[2]=m02; o[3]=mu0;
        o[4]=m01; o[5]=m11; o[6]=m12; o[7]=mu1;
        o[8]=m02; o[9]=m12; o[10]=m22; o[11]=mu2;
        o[12]=mu0; o[13]=mu1; o[14]=mu2; o[15]=1.0f;
    }
    __syncthreads();
    int so0 = (stype == 0) ? 0 : (stype == 1) ? 1 : 3;
    int ndup = (stype == 0) ? 1 : (stype == 1) ? 2 : 3;
    int total = 400 * ndup;
    size_t obase = (size_t)b * 36000 + (size_t)chunk * 80;
    for (int idx = tid; idx < total; idx += 256) {
        int dup = idx / 400;
        int r = idx % 400;
        int np = r / 80;
        int rem = r % 80;
        out[obase + (size_t)(so0 + dup) * 6000 + (size_t)np * 1200 + rem] = outm[r];
    }
}

// ---------------- Host ----------------
static void build_tab(Tab& tab) {
    unsigned char isb[2049];
    for (int i = 0; i <= 2048; ++i) isb[i] = 0;
    isb[2048] = 1;
    for (int k = 1; k <= 14; ++k) { isb[45 * k] = 1; isb[68 * k] = 1; isb[136 * k] = 1; }
    int n = 0, prev = 0;
    int pf0[NSEG_MAX];
    for (int f = 1; f <= 2048; ++f) {
        if (!isb[f]) continue;
        pf0[n] = prev;
        tab.p[n++] = (uint32_t)(prev | ((f - prev) << 16));
        prev = f;
    }
    tab.n = n;   // 36
    const int nst[3] = {136, 68, 45};
    for (int st = 0; st < 3; ++st) {
        int ns = nst[st];
        for (int c = 0; c < 15; ++c) {
            int a = c * ns, bnd = (c == 14) ? 2048 : (c + 1) * ns;
            int p0 = 0; while (p0 < n && pf0[p0] < a) ++p0;
            int p1 = p0; while (p1 < n && pf0[p1] < bnd) ++p1;
            tab.cr[st * 15 + c] = (uint32_t)(p0 | (p1 << 16));
        }
    }
}

extern "C" void kernel_launch(void* const* d_in, const int* in_sizes, int n_in,
                              void* d_out, int out_size, void* d_ws, size_t ws_size,
                              hipStream_t stream) {
    const float* x = (const float*)d_in[0];
    float* out = (float*)d_out;
    Tab tab;
    build_tab(tab);
    size_t ws_floats = (size_t)256 * tab.n * 225;
    size_t need = ws_floats * sizeof(float) + 256 * sizeof(unsigned);   // ~8.3 MB + counters

    if (ws_size >= need) {
        float* ws = (float*)d_ws;
        unsigned* cnt = (unsigned*)((char*)d_ws + ws_floats * sizeof(float));
        // ws is poisoned by the harness each iteration; counters must start at 0.
        hipMemsetAsync(cnt, 0, 256 * sizeof(unsigned), stream);
        dim3 g(tab.n, 256);
        fused_kernel<<<g, 256, 0, stream>>>(x, ws, cnt, out, tab);
    } else {
        gauss_fallback<<<256 * 45, 256, 0, stream>>>(x, out);
    }
}

// Round 2
// 279.243 us; speedup vs baseline: 2.9313x; 2.9313x over previous
//
#include <hip/hip_runtime.h>
#include <stdint.h>

// Fused single-pass: out[b, seg, np, chunk, p, 4, 4] = mean over chunk frames
// of [x;1][x;1]^T.  stypes 0/1/2: chunk len 136/68/45, out segs {0},{1,2},
// {3,4,5}; tail chunks run to T=2048.
//
// Phase A (all blocks, grid (piece, b) = 36 x 256): thread t<250 =
// (fslot=t/25, j=t%25) accumulates 9 moments in registers straight from
// global; per step k the block's 250 lanes read 750 contiguous floats.
// One LDS reduction -> 225-float ws slice per (b,piece), stored with
// AGENT-scope relaxed atomic stores (write-through past the non-coherent
// per-XCD L2 -- NO __threadfence: round-1 showed per-block device fences
// compile to buffer_wbl2/inv L2 flushes and cost ~700 us across 9216 blocks).
//
// Phase B (last-arriving block per b via relaxed agent-scope atomic counter):
// gathers the 36 piece slices (agent-scope loads, served from the coherent
// point), reduces piece->chunk, finalizes 4x4s, coalesced float4 stores for
// all 5 np.  Visibility argument: __syncthreads() drains vmcnt(0), so every
// block's write-through ws stores are globally visible before its counter
// tick; the winner therefore reads completed data.

#define NSEG_MAX 40
#define IDXPK 0x9210287517640543ull   // 4x4 row r -> moment idx nibbles (9=dummy)

struct Tab {
    int n;                        // 36
    uint32_t p[NSEG_MAX];         // f0 | (len<<16)
    uint32_t cr[45];              // per (stype*15+chunk): pstart | (pend<<16)
};

// ---------------- Fused kernel ----------------
__global__ __launch_bounds__(256) void fused_kernel(const float* __restrict__ x,
                                                    float* __restrict__ ws,
                                                    unsigned* __restrict__ cnt,
                                                    float* __restrict__ out, Tab tab) {
    // Overlaid LDS: phase A uses [0,2250); phase B uses sws[0,1800) +
    // red[1800,3825) + invn[3825,3870).  15.5 KB -> still 8 blocks/CU.
    __shared__ float smem[3870];
    __shared__ int lastFlag;
    int pc = blockIdx.x, b = blockIdx.y;
    int n = tab.n;
    uint32_t pk = tab.p[pc];
    int f0 = pk & 0xffff, L = (int)(pk >> 16);   // 8 <= L <= 144
    int tid = threadIdx.x;

    // ---- Phase A: per-(b,piece) moment sums ----
    if (tid < 250) {
        int fslot = tid / 25;                    // 0..9
        const float* q = x + (size_t)b * 153600 + (size_t)f0 * 75 + tid * 3;
        int nk = (L - fslot + 9) / 10;           // frames fslot, fslot+10, ...
        float s0=0.f,s1=0.f,s2=0.f,s3=0.f,s4=0.f,s5=0.f,s6=0.f,s7=0.f,s8=0.f;
        #pragma unroll 5
        for (int k = 0; k < nk; ++k, q += 750) {
            float a = q[0], bb = q[1], c = q[2];
            s0 += a;       s1 += bb;      s2 += c;
            s3 += a * a;   s4 += a * bb;  s5 += a * c;
            s6 += bb * bb; s7 += bb * c;  s8 += c * c;
        }
        float* l = &smem[tid * 9];               // stride 9: conflict-benign
        l[0]=s0; l[1]=s1; l[2]=s2; l[3]=s3; l[4]=s4; l[5]=s5; l[6]=s6; l[7]=s7; l[8]=s8;
    }
    __syncthreads();
    if (tid < 225) {              // cell = j*9+si ; partial at smem[fs*225+cell]
        float v = 0.f;
        #pragma unroll
        for (int fs = 0; fs < 10; ++fs) v += smem[fs * 225 + tid];
        // Device-coherent store (write-through): visible agent-wide once
        // vmcnt drains -- which __syncthreads below guarantees.
        __hip_atomic_store(&ws[((size_t)b * n + pc) * 225 + tid], v,
                           __ATOMIC_RELAXED, __HIP_MEMORY_SCOPE_AGENT);
    }
    __syncthreads();              // drains vmcnt(0): ws stores globally visible

    // ---- arrival: last block per b proceeds to phase B (no fences!) ----
    if (tid == 0) {
        unsigned old = __hip_atomic_fetch_add(&cnt[b], 1u,
                                              __ATOMIC_RELAXED, __HIP_MEMORY_SCOPE_AGENT);
        lastFlag = (old == (unsigned)(n - 1));
    }
    __syncthreads();
    if (!lastFlag) return;

    // ---- Phase B: finalize all 5 np for this b ----
    float* sws  = smem;           // [piece][j_local*9+si], n*45
    float* red  = smem + 1800;    // [stype*15+chunk][j_local*9+si]
    float* invn = smem + 3825;
    if (tid < 45) {
        int st = tid / 15, ch = tid - st * 15;
        const int nst[3] = {136, 68, 45};
        int ns = nst[st];
        int nfr = (ch == 14) ? (2048 - 14 * ns) : ns;
        invn[tid] = 1.0f / (float)nfr;
    }
    const float* wbase = ws + (size_t)b * n * 225;
    float4* ob4b = (float4*)(out + (size_t)b * 36000);
    int tot = n * 45;
    for (int np = 0; np < 5; ++np) {
        for (int i = tid; i < tot; i += 256) {
            int piece = i / 45, idx = i - piece * 45;
            sws[i] = __hip_atomic_load(&wbase[(size_t)piece * 225 + np * 45 + idx],
                                       __ATOMIC_RELAXED, __HIP_MEMORY_SCOPE_AGENT);
        }
        __syncthreads();          // (first iter: also covers invn)
        for (int i = tid; i < 2025; i += 256) {
            int sc = i / 45, idx = i - sc * 45;
            uint32_t r = tab.cr[sc];
            int p0 = (int)(r & 0xffff), p1 = (int)(r >> 16);
            float v = 0.f;
            for (int p = p0; p < p1; ++p) v += sws[p * 45 + idx];
            red[i] = v;
        }
        __syncthreads();
        // 1800 float4 stores: q -> (seg, chunk, p, row)
        float4* ob4 = ob4b + (size_t)np * 300;    // np*1200 floats
        for (int q = tid; q < 1800; q += 256) {
            int seg = q / 300;
            int q2  = q - seg * 300;              // ch*20 + p*4 + r
            int ch  = q2 / 20;
            int rem = q2 - ch * 20;
            int p   = rem >> 2;
            int r   = rem & 3;
            int st  = (seg == 0) ? 0 : (seg < 3) ? 1 : 2;
            int sc  = st * 15 + ch;
            float inv = invn[sc];
            const float* rb = &red[sc * 45 + p * 9];
            uint64_t pkk = IDXPK >> (16 * r);
            float4 v;
            v.x = rb[(int)(pkk & 15)] * inv;
            v.y = rb[(int)((pkk >> 4) & 15)] * inv;
            v.z = rb[(int)((pkk >> 8) & 15)] * inv;
            v.w = (r == 3) ? 1.0f : rb[(int)((pkk >> 12) & 15)] * inv;
            ob4[(size_t)seg * 1500 + q2] = v;
        }
        __syncthreads();          // red is rewritten next np while stores read it
    }
}

// ---------------- Fallback (round-1 fused, known-correct, no ws) ----------------
__global__ __launch_bounds__(256) void gauss_fallback(const float* __restrict__ x,
                                                      float* __restrict__ out) {
    __shared__ float lds[2250];
    __shared__ float red[225];
    __shared__ float outm[400];
    int bid = blockIdx.x;
    int chunk = bid % 15;
    int tmp = bid / 15;
    int stype = tmp % 3;
    int b = tmp / 3;
    const int nbs[3] = {136, 68, 45};
    int ns = nbs[stype];
    int f0 = chunk * ns;
    int f1 = (chunk == 14) ? 2048 : (f0 + ns);
    float inv_n = 1.0f / (float)(f1 - f0);
    int tid = threadIdx.x;
    if (tid < 250) {
        int j = tid % 25, tsub = tid / 25;
        const float* base = x + (size_t)b * 153600 + j * 3;
        float s0=0.f,s1=0.f,s2=0.f,s3=0.f,s4=0.f,s5=0.f,s6=0.f,s7=0.f,s8=0.f;
        for (int t = f0 + tsub; t < f1; t += 10) {
            const float* p = base + (size_t)t * 75;
            float x0 = p[0], x1 = p[1], x2 = p[2];
            s0+=x0; s1+=x1; s2+=x2;
            s3+=x0*x0; s4+=x0*x1; s5+=x0*x2;
            s6+=x1*x1; s7+=x1*x2; s8+=x2*x2;
        }
        float* l = &lds[tid * 9];
        l[0]=s0; l[1]=s1; l[2]=s2; l[3]=s3; l[4]=s4; l[5]=s5; l[6]=s6; l[7]=s7; l[8]=s8;
    }
    __syncthreads();
    if (tid < 225) {
        float v = 0.f;
        #pragma unroll
        for (int ts = 0; ts < 10; ++ts) v += lds[ts * 225 + tid];
        red[tid] = v;
    }
    __syncthreads();
    if (tid < 25) {
        const float* r = &red[tid * 9];
        float mu0=r[0]*inv_n, mu1=r[1]*inv_n, mu2=r[2]*inv_n;
        float m00=r[3]*inv_n, m01=r[4]*inv_n, m02=r[5]*inv_n;
        float m11=r[6]*inv_n, m12=r[7]*inv_n, m22=r[8]*inv_n;
        float* o = &outm[tid * 16];
        o[0]=m00; o[1]=m01; o[2]=m02; o[3]=mu0;
        o[4]=m01; o[5]=m11; o[6]=m12; o[7]=mu1;
        o[8]=m02; o[9]=m12; o[10]=m22; o[11]=mu2;
        o[12]=mu0; o[13]=mu1; o[14]=mu2; o[15]=1.0f;
    }
    __syncthreads();
    int so0 = (stype == 0) ? 0 : (stype == 1) ? 1 : 3;
    int ndup = (stype == 0) ? 1 : (stype == 1) ? 2 : 3;
    int total = 400 * ndup;
    size_t obase = (size_t)b * 36000 + (size_t)chunk * 80;
    for (int idx = tid; idx < total; idx += 256) {
        int dup = idx / 400;
        int r = idx % 400;
        int np = r / 80;
        int rem = r % 80;
        out[obase + (size_t)(so0 + dup) * 6000 + (size_t)np * 1200 + rem] = outm[r];
    }
}

// ---------------- Host ----------------
static void build_tab(Tab& tab) {
    unsigned char isb[2049];
    for (int i = 0; i <= 2048; ++i) isb[i] = 0;
    isb[2048] = 1;
    for (int k = 1; k <= 14; ++k) { isb[45 * k] = 1; isb[68 * k] = 1; isb[136 * k] = 1; }
    int n = 0, prev = 0;
    int pf0[NSEG_MAX];
    for (int f = 1; f <= 2048; ++f) {
        if (!isb[f]) continue;
        pf0[n] = prev;
        tab.p[n++] = (uint32_t)(prev | ((f - prev) << 16));
        prev = f;
    }
    tab.n = n;   // 36
    const int nst[3] = {136, 68, 45};
    for (int st = 0; st < 3; ++st) {
        int ns = nst[st];
        for (int c = 0; c < 15; ++c) {
            int a = c * ns, bnd = (c == 14) ? 2048 : (c + 1) * ns;
            int p0 = 0; while (p0 < n && pf0[p0] < a) ++p0;
            int p1 = p0; while (p1 < n && pf0[p1] < bnd) ++p1;
            tab.cr[st * 15 + c] = (uint32_t)(p0 | (p1 << 16));
        }
    }
}

extern "C" void kernel_launch(void* const* d_in, const int* in_sizes, int n_in,
                              void* d_out, int out_size, void* d_ws, size_t ws_size,
                              hipStream_t stream) {
    const float* x = (const float*)d_in[0];
    float* out = (float*)d_out;
    Tab tab;
    build_tab(tab);
    size_t ws_floats = (size_t)256 * tab.n * 225;
    size_t need = ws_floats * sizeof(float) + 256 * sizeof(unsigned);   // ~8.3 MB + counters

    if (ws_size >= need) {
        float* ws = (float*)d_ws;
        unsigned* cnt = (unsigned*)((char*)d_ws + ws_floats * sizeof(float));
        // ws is poisoned by the harness each iteration; counters must start at 0.
        hipMemsetAsync(cnt, 0, 256 * sizeof(unsigned), stream);
        dim3 g(tab.n, 256);
        fused_kernel<<<g, 256, 0, stream>>>(x, ws, cnt, out, tab);
    } else {
        gauss_fallback<<<256 * 45, 256, 0, stream>>>(x, out);
    }
}

// Round 4
// 277.859 us; speedup vs baseline: 2.9459x; 1.0050x over previous
//
#include <hip/hip_runtime.h>
#include <stdint.h>

// Single no-workspace kernel.  out[b, seg, np, chunk, p, 4, 4] = mean over
// chunk frames of [x;1][x;1]^T.
//
// Reference semantics: for each segment length L in [T, T/2, T-T/2, T/3,
// T/3, T-2*(T/3)] with T=2048, nb_fr = L // 15; chunks 0..13 are nb_fr
// frames from the START of the full sequence; chunk 14 is the REST of the
// full sequence (to frame 2048).  Hence segments with equal nb_fr are exact
// duplicates: stype0 (nb_fr=136) -> seg {0}; stype1 (nb_fr=68) -> segs
// {1,2}; stype2 (nb_fr=45) -> segs {3,4,5}.
//
// Why no workspace: the timed region is BW-bound soup; the harness's
// ~600 MB/iter workspace poison fill dominates (rounds 0-2 model: total ~=
// total-HBM-bytes / 6.2 TB/s ~= 235 us with ws in play).  This kernel never
// touches d_ws.  x is 157 MB (< 256 MB Infinity Cache), so the 3 stype
// passes cost ~1x HBM + ~2x LLC.
//
// Round-1 lesson: no __threadfence anywhere (buffer_wbl2/inv storms).
// Round-3 lesson: no intra-dispatch cross-block producer/consumer on
// gfx950 -- relaxed agent-scope store->tick->poll->load raced; correct
// acquire/release needs the L2 flushes we can't afford.  This kernel has
// zero cross-block communication.
//
// Grid 256*45 blocks: (b, stype, chunk).  Thread t<250 = (tsub=t/25,
// j=t%25) accumulates 9 moments in registers straight from global; the
// block's 250 lanes cover 750 contiguous floats per frame-decade.  One LDS
// reduction, 25 lanes finalize 4x4s, duplicated stores to all segs of the
// stype.

__global__ __launch_bounds__(256) void gauss_fallback(const float* __restrict__ x,
                                                      float* __restrict__ out) {
    __shared__ float lds[2250];
    __shared__ float red[225];
    __shared__ float outm[400];
    int bid = blockIdx.x;
    int chunk = bid % 15;
    int tmp = bid / 15;
    int stype = tmp % 3;
    int b = tmp / 3;
    const int nbs[3] = {136, 68, 45};
    int ns = nbs[stype];
    int f0 = chunk * ns;
    int f1 = (chunk == 14) ? 2048 : (f0 + ns);
    float inv_n = 1.0f / (float)(f1 - f0);
    int tid = threadIdx.x;
    if (tid < 250) {
        int j = tid % 25, tsub = tid / 25;
        const float* base = x + (size_t)b * 153600 + j * 3;
        float s0=0.f,s1=0.f,s2=0.f,s3=0.f,s4=0.f,s5=0.f,s6=0.f,s7=0.f,s8=0.f;
        for (int t = f0 + tsub; t < f1; t += 10) {
            const float* p = base + (size_t)t * 75;
            float x0 = p[0], x1 = p[1], x2 = p[2];
            s0+=x0; s1+=x1; s2+=x2;
            s3+=x0*x0; s4+=x0*x1; s5+=x0*x2;
            s6+=x1*x1; s7+=x1*x2; s8+=x2*x2;
        }
        float* l = &lds[tid * 9];
        l[0]=s0; l[1]=s1; l[2]=s2; l[3]=s3; l[4]=s4; l[5]=s5; l[6]=s6; l[7]=s7; l[8]=s8;
    }
    __syncthreads();
    if (tid < 225) {
        float v = 0.f;
        #pragma unroll
        for (int ts = 0; ts < 10; ++ts) v += lds[ts * 225 + tid];
        red[tid] = v;
    }
    __syncthreads();
    if (tid < 25) {
        const float* r = &red[tid * 9];
        float mu0=r[0]*inv_n, mu1=r[1]*inv_n, mu2=r[2]*inv_n;
        float m00=r[3]*inv_n, m01=r[4]*inv_n, m02=r[5]*inv_n;
        float m11=r[6]*inv_n, m12=r[7]*inv_n, m22=r[8]*inv_n;
        float* o = &outm[tid * 16];
        o[0]=m00; o[1]=m01; o[2]=m02; o[3]=mu0;
        o[4]=m01; o[5]=m11; o[6]=m12; o[7]=mu1;
        o[8]=m02; o[9]=m12; o[10]=m22; o[11]=mu2;
        o[12]=mu0; o[13]=mu1; o[14]=mu2; o[15]=1.0f;
    }
    __syncthreads();
    int so0 = (stype == 0) ? 0 : (stype == 1) ? 1 : 3;
    int ndup = (stype == 0) ? 1 : (stype == 1) ? 2 : 3;
    int total = 400 * ndup;
    size_t obase = (size_t)b * 36000 + (size_t)chunk * 80;
    for (int idx = tid; idx < total; idx += 256) {
        int dup = idx / 400;
        int r = idx % 400;
        int np = r / 80;
        int rem = r % 80;
        out[obase + (size_t)(so0 + dup) * 6000 + (size_t)np * 1200 + rem] = outm[r];
    }
}

extern "C" void kernel_launch(void* const* d_in, const int* in_sizes, int n_in,
                              void* d_out, int out_size, void* d_ws, size_t ws_size,
                              hipStream_t stream) {
    const float* x = (const float*)d_in[0];
    float* out = (float*)d_out;
    (void)d_ws; (void)ws_size;   // deliberately unused: testing whether the
                                 // ~600 MB/iter ws poison is usage-conditional
    gauss_fallback<<<256 * 45, 256, 0, stream>>>(x, out);
}

// Round 5
// 238.335 us; speedup vs baseline: 3.4344x; 1.1658x over previous
//
#include <hip/hip_runtime.h>
#include <stdint.h>

// Two-kernel pipeline (restored round-0 structure -- the proven optimum).
// out[b, seg, np, chunk, p, 4, 4] = mean over chunk frames of [x;1][x;1]^T
// (cov + mu muT == E[y yT]).  stypes 0/1/2: chunk len 136/68/45, out segs
// {0},{1,2},{3,4,5}.  Tail chunks run to T=2048.
//
// Session ledger (why this shape):
//  r0  two-kernel: total 239.5 us, p1+p2 ~45-50 (both < 94, under the fills)
//  r1  fused + __threadfence per block: 758 us kernel -- agent fences emit
//      buffer_wbl2/inv L2 flushes; NEVER use per-block device fences.
//  r2  fused + sc1 stores, serial 256-block B tail: 135 us kernel (tail ~100).
//  r3  fused + 1280 polling B-blocks: FAILED -- relaxed agent store->tick->
//      poll->load is not acq/rel on gfx950; intra-dispatch cross-block
//      producer/consumer is unsound here.  Dispatch boundary IS sound.
//  r4  single no-ws kernel: 117.5 us (chunk-14 stragglers read 1096/1418
//      frames); overhead ledger r0/r2/r4 = ~192/144/160 us => the ~600 MB ws
//      poison fill is NOT usage-conditional.  Using d_ws costs nothing.
// => minimize kernel time with the dispatch-boundary-coherent two-kernel
//    pipeline; harness poison (~95 us fills) is the uncontrollable floor.
//
// p1: grid (piece, b) = 36 x 256, 256 thr.  pieces = union of all chunk
//     boundaries (36 segments, 8..144 frames, never cross any chunk edge).
//     Thread t<250 = (fslot=t/25, j=t%25) accumulates 9 moments in REGISTERS
//     straight from global: per step k the block's 250 lanes read floats
//     f0*75+3t+750k .. +749 -- perfectly contiguous, no LDS in the load path.
//     One LDS reduction at the end -> 225-float slice of ws.
// p2: per (b,np) = 1280 blocks: gather contiguous piece-range sums per chunk
//     (host-precomputed ranges), finalize 4x4s, coalesced float4 stores.

#define NSEG_MAX 40
#define IDXPK 0x9210287517640543ull   // 4x4 row r -> moment idx nibbles (9=dummy)

struct Tab {
    int n;                        // 36
    uint32_t p[NSEG_MAX];         // f0 | (len<<16)
    uint32_t cr[45];              // per (stype*15+chunk): pstart | (pend<<16)
};

// ---------------- Phase 1 ----------------
__global__ __launch_bounds__(256) void p1_kernel(const float* __restrict__ x,
                                                 float* __restrict__ ws, Tab tab) {
    __shared__ float lds[2250];   // [250 threads][9]
    int pc = blockIdx.x, b = blockIdx.y;
    uint32_t pk = tab.p[pc];
    int f0 = pk & 0xffff, L = (int)(pk >> 16);   // 8 <= L <= 144
    int tid = threadIdx.x;

    if (tid < 250) {
        int fslot = tid / 25;                    // 0..9
        const float* q = x + (size_t)b * 153600 + (size_t)f0 * 75 + tid * 3;
        int nk = (L - fslot + 9) / 10;           // frames fslot, fslot+10, ...
        float s0=0.f,s1=0.f,s2=0.f,s3=0.f,s4=0.f,s5=0.f,s6=0.f,s7=0.f,s8=0.f;
        #pragma unroll 5
        for (int k = 0; k < nk; ++k, q += 750) {
            float a = q[0], bb = q[1], c = q[2];
            s0 += a;       s1 += bb;      s2 += c;
            s3 += a * a;   s4 += a * bb;  s5 += a * c;
            s6 += bb * bb; s7 += bb * c;  s8 += c * c;
        }
        float* l = &lds[tid * 9];                // stride 9: conflict-benign
        l[0]=s0; l[1]=s1; l[2]=s2; l[3]=s3; l[4]=s4; l[5]=s5; l[6]=s6; l[7]=s7; l[8]=s8;
    }
    __syncthreads();
    if (tid < 225) {              // cell = j*9+si ; partial at lds[fs*225+cell]
        float v = 0.f;
        #pragma unroll
        for (int fs = 0; fs < 10; ++fs) v += lds[fs * 225 + tid];
        ws[((size_t)b * tab.n + pc) * 225 + tid] = v;   // plain store: dispatch
    }                                                   // boundary = coherence
}

// ---------------- Phase 2: per (b, np) ----------------
__global__ __launch_bounds__(256) void p2_kernel(const float* __restrict__ ws,
                                                 float* __restrict__ out, Tab tab) {
    __shared__ float sws[1620];   // [piece][j_local*9+si], 36*45
    __shared__ float red[2032];   // [stype*15+chunk][j_local*9+si] (+pad)
    __shared__ float invn[45];
    int b = blockIdx.x, np = blockIdx.y;
    int tid = threadIdx.x;
    int n = tab.n;
    int tot = n * 45;
    const float* wb = ws + (size_t)b * n * 225 + np * 45;
    for (int i = tid; i < tot; i += 256) {
        int piece = i / 45, idx = i - piece * 45;
        sws[i] = wb[(size_t)piece * 225 + idx];   // 180 B contiguous runs
    }
    if (tid < 45) {
        int st = tid / 15, ch = tid - st * 15;
        const int nst[3] = {136, 68, 45};
        int ns = nst[st];
        int nfr = (ch == 14) ? (2048 - 14 * ns) : ns;
        invn[tid] = 1.0f / (float)nfr;
    }
    __syncthreads();

    for (int i = tid; i < 2025; i += 256) {
        int sc = i / 45, idx = i - sc * 45;
        uint32_t r = tab.cr[sc];
        int p0 = (int)(r & 0xffff), p1 = (int)(r >> 16);
        float v = 0.f;
        for (int p = p0; p < p1; ++p) v += sws[p * 45 + idx];
        red[i] = v;
    }
    __syncthreads();

    // 1800 float4 stores per block: q -> (seg, chunk, p, row)
    float4* ob4 = (float4*)(out + (size_t)b * 36000 + (size_t)np * 1200);
    for (int q = tid; q < 1800; q += 256) {
        int seg = q / 300;
        int q2  = q - seg * 300;        // ch*20 + p*4 + r
        int ch  = q2 / 20;
        int rem = q2 - ch * 20;
        int p   = rem >> 2;
        int r   = rem & 3;
        int st  = (seg == 0) ? 0 : (seg < 3) ? 1 : 2;
        int sc  = st * 15 + ch;
        float inv = invn[sc];
        const float* rb = &red[sc * 45 + p * 9];
        uint64_t pkk = IDXPK >> (16 * r);
        float4 v;
        v.x = rb[(int)(pkk & 15)] * inv;
        v.y = rb[(int)((pkk >> 4) & 15)] * inv;
        v.z = rb[(int)((pkk >> 8) & 15)] * inv;
        v.w = (r == 3) ? 1.0f : rb[(int)((pkk >> 12) & 15)] * inv;
        ob4[(size_t)seg * 1500 + q2] = v;
    }
}

// ---------------- Fallback (known-correct, no ws) ----------------
__global__ __launch_bounds__(256) void gauss_fallback(const float* __restrict__ x,
                                                      float* __restrict__ out) {
    __shared__ float lds[2250];
    __shared__ float red[225];
    __shared__ float outm[400];
    int bid = blockIdx.x;
    int chunk = bid % 15;
    int tmp = bid / 15;
    int stype = tmp % 3;
    int b = tmp / 3;
    const int nbs[3] = {136, 68, 45};
    int ns = nbs[stype];
    int f0 = chunk * ns;
    int f1 = (chunk == 14) ? 2048 : (f0 + ns);
    float inv_n = 1.0f / (float)(f1 - f0);
    int tid = threadIdx.x;
    if (tid < 250) {
        int j = tid % 25, tsub = tid / 25;
        const float* base = x + (size_t)b * 153600 + j * 3;
        float s0=0.f,s1=0.f,s2=0.f,s3=0.f,s4=0.f,s5=0.f,s6=0.f,s7=0.f,s8=0.f;
        for (int t = f0 + tsub; t < f1; t += 10) {
            const float* p = base + (size_t)t * 75;
            float x0 = p[0], x1 = p[1], x2 = p[2];
            s0+=x0; s1+=x1; s2+=x2;
            s3+=x0*x0; s4+=x0*x1; s5+=x0*x2;
            s6+=x1*x1; s7+=x1*x2; s8+=x2*x2;
        }
        float* l = &lds[tid * 9];
        l[0]=s0; l[1]=s1; l[2]=s2; l[3]=s3; l[4]=s4; l[5]=s5; l[6]=s6; l[7]=s7; l[8]=s8;
    }
    __syncthreads();
    if (tid < 225) {
        float v = 0.f;
        #pragma unroll
        for (int ts = 0; ts < 10; ++ts) v += lds[ts * 225 + tid];
        red[tid] = v;
    }
    __syncthreads();
    if (tid < 25) {
        const float* r = &red[tid * 9];
        float mu0=r[0]*inv_n, mu1=r[1]*inv_n, mu2=r[2]*inv_n;
        float m00=r[3]*inv_n, m01=r[4]*inv_n, m02=r[5]*inv_n;
        float m11=r[6]*inv_n, m12=r[7]*inv_n, m22=r[8]*inv_n;
        float* o = &outm[tid * 16];
        o[0]=m00; o[1]=m01; o[2]=m02; o[3]=mu0;
        o[4]=m01; o[5]=m11; o[6]=m12; o[7]=mu1;
        o[8]=m02; o[9]=m12; o[10]=m22; o[11]=mu2;
        o[12]=mu0; o[13]=mu1; o[14]=mu2; o[15]=1.0f;
    }
    __syncthreads();
    int so0 = (stype == 0) ? 0 : (stype == 1) ? 1 : 3;
    int ndup = (stype == 0) ? 1 : (stype == 1) ? 2 : 3;
    int total = 400 * ndup;
    size_t obase = (size_t)b * 36000 + (size_t)chunk * 80;
    for (int idx = tid; idx < total; idx += 256) {
        int dup = idx / 400;
        int r = idx % 400;
        int np = r / 80;
        int rem = r % 80;
        out[obase + (size_t)(so0 + dup) * 6000 + (size_t)np * 1200 + rem] = outm[r];
    }
}

// ---------------- Host ----------------
static void build_tab(Tab& tab) {
    unsigned char isb[2049];
    for (int i = 0; i <= 2048; ++i) isb[i] = 0;
    isb[2048] = 1;
    for (int k = 1; k <= 14; ++k) { isb[45 * k] = 1; isb[68 * k] = 1; isb[136 * k] = 1; }
    int n = 0, prev = 0;
    int pf0[NSEG_MAX];
    for (int f = 1; f <= 2048; ++f) {
        if (!isb[f]) continue;
        pf0[n] = prev;
        tab.p[n++] = (uint32_t)(prev | ((f - prev) << 16));
        prev = f;
    }
    tab.n = n;   // 36
    const int nst[3] = {136, 68, 45};
    for (int st = 0; st < 3; ++st) {
        int ns = nst[st];
        for (int c = 0; c < 15; ++c) {
            int a = c * ns, bnd = (c == 14) ? 2048 : (c + 1) * ns;
            int p0 = 0; while (p0 < n && pf0[p0] < a) ++p0;
            int p1 = p0; while (p1 < n && pf0[p1] < bnd) ++p1;
            tab.cr[st * 15 + c] = (uint32_t)(p0 | (p1 << 16));
        }
    }
}

extern "C" void kernel_launch(void* const* d_in, const int* in_sizes, int n_in,
                              void* d_out, int out_size, void* d_ws, size_t ws_size,
                              hipStream_t stream) {
    const float* x = (const float*)d_in[0];
    float* out = (float*)d_out;
    Tab tab;
    build_tab(tab);
    size_t need = (size_t)256 * tab.n * 225 * sizeof(float);   // ~8.3 MB

    if (ws_size >= need) {
        float* ws = (float*)d_ws;
        dim3 g1(tab.n, 256);
        p1_kernel<<<g1, 256, 0, stream>>>(x, ws, tab);
        dim3 g2(256, 5);
        p2_kernel<<<g2, 256, 0, stream>>>(ws, out, tab);
    } else {
        gauss_fallback<<<256 * 45, 256, 0, stream>>>(x, out);
    }
}